// Round 12
// baseline (265.642 us; speedup 1.0000x reference)
//
#include <hip/hip_runtime.h>

// ---- problem geometry ----
#define NTIPS 512
#define DIM   510                     // internal nodes = ntips - 2
#define TOTAL 1022
#define BS    64
#define ITERS 50

// ---- chunk config: 8-feat slabs (R4/R7/R9/R10-proven uint2 body), dbuf ----
#define NSLAB 64
#define NWG   (BS * NSLAB)            // 4096 workgroups
#define NPART ((size_t)ITERS * BS * NSLAB)
#define ROWEL 8                       // u16 per row-slab (16 B)
#define XSEC   (DIM * ROWEL)          // 4080 u16
#define ONEOFF XSEC                   // 8 one-hot const rows
#define ZROW   (XSEC + 8 * ROWEL)     // all-zero const row
#define BSTRIDE (XSEC + 9 * ROWEL)    // 4152 u16 per LDS buffer
#define BUFB   (BSTRIDE * 2)          // 8304 B per buffer (2 buffers = 16.6KB)
#define WGB    (DIM * ROWEL * 2)      // 8160 B per WG region in a slot
#define XB     ((size_t)BS * DIM * NTIPS)  // u16 per snapshot slot
#define SLOTB  (XB * 2)               // 33.4 MB per slot

// ---- phaseC config: 16-feat slabs, single-buffer ----
#define NSLAB2 32
#define NWG2   (BS * NSLAB2)          // 2048 workgroups
#define ROWEL2 16
#define XSEC2  (DIM * ROWEL2)         // 8160 u16
#define ONE2   XSEC2
#define ZROW2  (XSEC2 + 16 * ROWEL2)
#define BSTR2  (XSEC2 + 17 * ROWEL2)  // 8432 u16 = 16864 B

typedef unsigned short u16;
typedef unsigned int   u32;
typedef float f32x2 __attribute__((ext_vector_type(2)));

// bf16 RNE helpers (validated chain)
__device__ __forceinline__ u16 f2bf(float x) {
    u32 u = __float_as_uint(x);
    return (u16)((u + 0x7FFFu + ((u >> 16) & 1u)) >> 16);
}
__device__ __forceinline__ float bf2f(u16 h) { return __uint_as_float(((u32)h) << 16); }
__device__ __forceinline__ float bflo(u32 p) { return __uint_as_float(p << 16); }
__device__ __forceinline__ float bfhi(u32 p) { return __uint_as_float(p & 0xFFFF0000u); }
__device__ __forceinline__ f32x2 unpk(u32 p) {
    f32x2 r; r.x = bflo(p); r.y = bfhi(p); return r;
}

#if defined(__has_builtin)
#  if __has_builtin(__builtin_amdgcn_cvt_pk_bf16_f32)
#    define HAVE_PKBF 1
#  endif
#endif
#ifdef HAVE_PKBF
typedef __bf16 bf16x2 __attribute__((ext_vector_type(2)));
__device__ __forceinline__ u32 pkbf(float a, float b) {   // lo=a, hi=b, RNE
    bf16x2 r = __builtin_amdgcn_cvt_pk_bf16_f32(a, b);
    return __builtin_bit_cast(u32, r);
}
#else
__device__ __forceinline__ u32 pkbf(float a, float b) {
    return (u32)f2bf(a) | ((u32)f2bf(b) << 16);
}
#endif

// correctly-rounded f32 /3 (Markstein mul+2fma) — R2..R11-validated
__device__ __forceinline__ f32x2 div3v(f32x2 x) {
    const float C = 0x1.555556p-2f;               // RN(1/3)
    f32x2 q0, r, q;
    q0.x = x.x * C;             q0.y = x.y * C;
    r.x = fmaf(-3.f, q0.x, x.x); r.y = fmaf(-3.f, q0.y, x.y);
    q.x = fmaf(r.x, C, q0.x);    q.y = fmaf(r.y, C, q0.y);
    return q;
}
// no-delta packed-pair step (phaseC)
__device__ __forceinline__ u32 stepND(u32 a0, u32 a1, u32 a2) {
    const f32x2 a = (unpk(a0) + unpk(a1)) + unpk(a2);
    const f32x2 q = div3v(a);
    return pkbf(q.x, q.y);
}

// LDS-only barrier (R3..R11-validated): no vmcnt drain
__device__ __forceinline__ void barrier_lds_only() {
    __builtin_amdgcn_sched_barrier(0);
    asm volatile("s_waitcnt lgkmcnt(0)" ::: "memory");
    __builtin_amdgcn_s_barrier();
    __builtin_amdgcn_sched_barrier(0);
}

// Surviving-checkpoint map (R12):
//  live12 leaves cp11 (slot 1) + cp12 (slot 0).
//  tail (if it ran) leaves cp44 (slot 0) + cp50 (slot 1).
//  Any other S: resume from X0 (slow-but-correct; never taken for this data).
__device__ __forceinline__ void resolveS(int S, int& T, int& slot, int& fromX0) {
    fromX0 = 0;
    if (S >= 50)      { T = 0;      slot = 1; }
    else if (S >= 44) { T = S - 44; slot = 0; }
    else if (S == 12) { T = 0;      slot = 0; }
    else if (S == 11) { T = 0;      slot = 1; }
    else              { T = S;      slot = 0; fromX0 = 1; }
}

// gather offsets for 8-feat slabs (BYTE units, buffer-relative) — R4-proven
__device__ __forceinline__ void make_offsets8(const int* __restrict__ edge,
        int b, int sl, int rg, int lbyte, int nr, u32 offB[4][3]) {
    #pragma unroll
    for (int k = 0; k < 4; ++k) if (k < nr) {
        const int i = rg + 128 * k;
        const int* ep = edge + ((size_t)b * TOTAL + NTIPS + i) * 3;
        #pragma unroll
        for (int t = 0; t < 3; ++t) {
            const int e = ep[t];
            u32 off;
            if (e >= NTIPS)          off = (u32)((e - NTIPS) * ROWEL);
            else if ((e >> 3) == sl) off = (u32)(ONEOFF + (e & 7) * ROWEL);
            else                     off = (u32)ZROW;
            offB[k][t] = off * 2u + (u32)lbyte;
        }
    }
}

__device__ __forceinline__ void init_const_rows8(u16* X, int tid) {
    for (int j = tid; j < 9 * ROWEL; j += 256) {
        const int row = j >> 3, col = j & 7;
        const u16 v = (row == col) ? (u16)0x3F80 : (u16)0;  // row 8 = zeros
        X[ONEOFF + j] = v;
        X[BSTRIDE + ONEOFF + j] = v;
    }
}

// ---------------------------------------------------------------------------
// live12: steps 1..12 in ONE launch (R10/R11-proven). Fused identity write
// (doIdent) + ctrl clear. Mid checkpoint step 11 -> slot 1 (was 9 — S is
// 11 or 12 per R0/R2 evidence, so this makes phaseCX's T=0 in both cases),
// end checkpoint step 12 -> slot 0.
// ---------------------------------------------------------------------------
__global__ __launch_bounds__(256, 8) void live12_kernel(
        const int* __restrict__ edge, float* __restrict__ partials,
        int* __restrict__ ctrl, u16* __restrict__ slots,
        float* __restrict__ out, int doIdent) {
    __shared__ u16 X[2 * BSTRIDE];
    __shared__ float redL[2][4];

    const int wg = blockIdx.x, b = wg >> 6, sl = wg & 63;
    const int tid = threadIdx.x, rg = tid >> 1;
    const int lbyte = (tid & 1) << 3;
    const int nr = (rg < 126) ? 4 : 3;
    char* Xc = reinterpret_cast<char*>(X);
    const u32 r0b = (u32)(rg * 16 + lbyte);

    if (wg == 0 && tid == 0) {               // ctrl clear (was host memset)
        ctrl[0] = 0; ctrl[1] = 0; ctrl[2] = 0; ctrl[3] = 0;
    }
    if (doIdent) {                           // identity stripe: rows sl*8..+7
        const int r = (sl << 3) + (tid >> 5);
        const int c0 = (tid & 31) << 4;      // 16 floats per thread
        float* drow = out + ((size_t)b * TOTAL + r) * NTIPS + c0;
        #pragma unroll
        for (int m = 0; m < 4; ++m) {
            const int cb = c0 + (m << 2);
            float4 v;
            v.x = (r == cb + 0) ? 1.f : 0.f;
            v.y = (r == cb + 1) ? 1.f : 0.f;
            v.z = (r == cb + 2) ? 1.f : 0.f;
            v.w = (r == cb + 3) ? 1.f : 0.f;
            *reinterpret_cast<float4*>(drow + (m << 2)) = v;
        }
    }

    u32 offB[4][3];
    make_offsets8(edge, b, sl, rg, lbyte, nr, offB);

    u32 rowByte[4];
    #pragma unroll
    for (int k = 0; k < 4; ++k)
        rowByte[k] = (u32)wg * (u32)WGB + (u32)((rg + 128 * k) * 16) + (u32)lbyte;

    for (int j = tid; j < XSEC / 2; j += 256)
        reinterpret_cast<u32*>(X)[j] = 0x3B003B00u;       // X0 = bf16(1/512)
    init_const_rows8(X, tid);

    f32x2 old01[4], old23[4];
    #pragma unroll
    for (int k = 0; k < 4; ++k) if (k < nr) {
        const uint2 ov = *reinterpret_cast<const uint2*>(Xc + r0b + (k << 11));
        old01[k] = unpk(ov.x); old23[k] = unpk(ov.y);
    }
    __syncthreads();

    char* slot1C = reinterpret_cast<char*>(slots) + SLOTB;   // step-11 cp
    #pragma unroll
    for (int u = 0; u < 12; ++u) {
        const int s = 1 + u;
        const int srcB = (u & 1) ? BUFB : 0;
        const int dstB = ((u + 1) & 1) ? BUFB : 0;
        float dacc = 0.f;
        #pragma unroll
        for (int k = 0; k < 4; ++k) if (k < nr) {
            const uint2 g0 = *reinterpret_cast<const uint2*>(Xc + offB[k][0] + srcB);
            const uint2 g1 = *reinterpret_cast<const uint2*>(Xc + offB[k][1] + srcB);
            const uint2 g2 = *reinterpret_cast<const uint2*>(Xc + offB[k][2] + srcB);
            const f32x2 a01 = (unpk(g0.x) + unpk(g1.x)) + unpk(g2.x);
            const f32x2 a23 = (unpk(g0.y) + unpk(g1.y)) + unpk(g2.y);
            const f32x2 q01 = div3v(a01), q23 = div3v(a23);
            uint2 nv;
            nv.x = pkbf(q01.x, q01.y);
            nv.y = pkbf(q23.x, q23.y);
            *reinterpret_cast<uint2*>(Xc + r0b + ((k << 11) + dstB)) = nv;
            if (u == 10)                             // step 11 checkpoint
                *reinterpret_cast<uint2*>(slot1C + rowByte[k]) = nv;
            const f32x2 n01 = unpk(nv.x), n23 = unpk(nv.y);
            const f32x2 d01v = n01 - old01[k];
            const f32x2 d23v = n23 - old23[k];
            const u32 d01 = pkbf(d01v.x, d01v.y);
            const u32 d23 = pkbf(d23v.x, d23v.y);
            dacc += fabsf(bflo(d01));
            dacc += fabsf(bfhi(d01));
            dacc += fabsf(bflo(d23));
            dacc += fabsf(bfhi(d23));
            old01[k] = n01; old23[k] = n23;
        }
        #pragma unroll
        for (int off = 32; off > 0; off >>= 1) dacc += __shfl_down(dacc, off);
        if ((tid & 63) == 0) redL[u & 1][tid >> 6] = dacc;
        barrier_lds_only();
        if (tid == 0) {
            const float dtot = ((redL[u & 1][0] + redL[u & 1][1])
                                + redL[u & 1][2]) + redL[u & 1][3];
            partials[((size_t)(s - 1) * BS + b) * NSLAB + sl] = dtot;
        }
    }

    // end checkpoint: step 12 (buffer 0) -> slot 0
    char* slot0C = reinterpret_cast<char*>(slots);
    #pragma unroll
    for (int k = 0; k < 4; ++k) if (k < nr)
        *reinterpret_cast<uint2*>(slot0C + rowByte[k]) =
            *reinterpret_cast<const uint2*>(Xc + r0b + (k << 11));
}

// ---------------------------------------------------------------------------
// tail: steps 13..50 in ONE gated launch. Checkpoints ONLY at 44 (slot 0)
// and 50 (slot 1) — the R10/R11 alternating schedule destroyed earlier cps
// (latent bug; S in (12,43] now correctly resumes from X0 in phaseCX).
// ---------------------------------------------------------------------------
__global__ __launch_bounds__(256, 8) void tail_kernel(
        const int* __restrict__ edge, float* __restrict__ partials,
        const int* __restrict__ ctrl, u16* __restrict__ slots) {
    if (ctrl[2] != 0) return;                    // common case: skip

    __shared__ u16 X[2 * BSTRIDE];
    __shared__ float redL[2][4];

    const int wg = blockIdx.x, b = wg >> 6, sl = wg & 63;
    const int tid = threadIdx.x, rg = tid >> 1;
    const int lbyte = (tid & 1) << 3;
    const int nr = (rg < 126) ? 4 : 3;
    char* Xc = reinterpret_cast<char*>(X);
    const u32 r0b = (u32)(rg * 16 + lbyte);

    u32 offB[4][3];
    make_offsets8(edge, b, sl, rg, lbyte, nr, offB);

    u32 rowByte[4];
    #pragma unroll
    for (int k = 0; k < 4; ++k)
        rowByte[k] = (u32)wg * (u32)WGB + (u32)((rg + 128 * k) * 16) + (u32)lbyte;

    {   // reload checkpoint step 12 (slot 0)
        const char* src0 = reinterpret_cast<const char*>(slots);
        #pragma unroll
        for (int k = 0; k < 4; ++k) if (k < nr)
            *reinterpret_cast<uint2*>(Xc + r0b + (k << 11)) =
                *reinterpret_cast<const uint2*>(src0 + rowByte[k]);
    }
    init_const_rows8(X, tid);

    f32x2 old01[4], old23[4];
    #pragma unroll
    for (int k = 0; k < 4; ++k) if (k < nr) {
        const uint2 ov = *reinterpret_cast<const uint2*>(Xc + r0b + (k << 11));
        old01[k] = unpk(ov.x); old23[k] = unpk(ov.y);
    }
    __syncthreads();

    u32 srcB = 0;
    for (int s = 13; s <= 50; ++s) {
        const u32 dstB = srcB ^ (u32)BUFB;
        float dacc = 0.f;
        #pragma unroll
        for (int k = 0; k < 4; ++k) if (k < nr) {
            const uint2 g0 = *reinterpret_cast<const uint2*>(Xc + offB[k][0] + srcB);
            const uint2 g1 = *reinterpret_cast<const uint2*>(Xc + offB[k][1] + srcB);
            const uint2 g2 = *reinterpret_cast<const uint2*>(Xc + offB[k][2] + srcB);
            const f32x2 a01 = (unpk(g0.x) + unpk(g1.x)) + unpk(g2.x);
            const f32x2 a23 = (unpk(g0.y) + unpk(g1.y)) + unpk(g2.y);
            const f32x2 q01 = div3v(a01), q23 = div3v(a23);
            uint2 nv;
            nv.x = pkbf(q01.x, q01.y);
            nv.y = pkbf(q23.x, q23.y);
            *reinterpret_cast<uint2*>(Xc + r0b + ((k << 11) + dstB)) = nv;
            const f32x2 n01 = unpk(nv.x), n23 = unpk(nv.y);
            const f32x2 d01v = n01 - old01[k];
            const f32x2 d23v = n23 - old23[k];
            const u32 d01 = pkbf(d01v.x, d01v.y);
            const u32 d23 = pkbf(d23v.x, d23v.y);
            dacc += fabsf(bflo(d01));
            dacc += fabsf(bfhi(d01));
            dacc += fabsf(bflo(d23));
            dacc += fabsf(bfhi(d23));
            old01[k] = n01; old23[k] = n23;
        }
        #pragma unroll
        for (int off = 32; off > 0; off >>= 1) dacc += __shfl_down(dacc, off);
        if ((tid & 63) == 0) redL[s & 1][tid >> 6] = dacc;
        barrier_lds_only();
        if (tid == 0) {
            const float dtot = ((redL[s & 1][0] + redL[s & 1][1])
                                + redL[s & 1][2]) + redL[s & 1][3];
            partials[((size_t)(s - 1) * BS + b) * NSLAB + sl] = dtot;
        }
        if (s == 44 || s == 50) {                // surviving cps only
            char* slotC = reinterpret_cast<char*>(slots)
                        + (size_t)(s == 50 ? 1 : 0) * SLOTB;
            #pragma unroll
            for (int k = 0; k < 4; ++k) if (k < nr)
                *reinterpret_cast<uint2*>(slotC + rowByte[k]) =
                    *reinterpret_cast<const uint2*>(Xc + r0b + ((k << 11) + dstB));
        }
        srcB = dstB;
    }
}

// ---------------------------------------------------------------------------
// findS: incremental (ctrl[3] = next unscanned s). EXACT decision math.
// ---------------------------------------------------------------------------
__global__ void findS_kernel(const float* __restrict__ partials,
                             int* __restrict__ ctrl, int smax) {
    if (ctrl[2] != 0) return;
    const int lane = threadIdx.x;
    const int sStart = (ctrl[3] > 1) ? ctrl[3] : 1;
    const float tol_bf = bf2f(f2bf(1e-5f));
    int S = -1;
    for (int s = sStart; s <= smax; ++s) {
        const float* p = partials + ((size_t)(s - 1) * BS + lane) * NSLAB;
        float t = 0.f;
        #pragma unroll
        for (int k = 0; k < NSLAB; ++k) t += p[k];
        const float lnorm = bf2f(f2bf(t / 261120.0f));
        if (__ballot(lnorm > tol_bf) == 0ULL) { S = s; break; }
    }
    if (S < 0 && smax == ITERS) S = ITERS;
    if (lane == 0) {
        if (S > 0) { ctrl[0] = S; ctrl[2] = 1; }
        else         ctrl[3] = smax + 1;
    }
}

// ---------------------------------------------------------------------------
// ident (fallback only): identity block, row-contiguous full-BW writer.
// ---------------------------------------------------------------------------
__global__ __launch_bounds__(256) void ident_kernel(float* __restrict__ out) {
    const size_t nf4 = (size_t)BS * NTIPS * NTIPS / 4;   // 4,194,304 float4
    for (size_t i = (size_t)blockIdx.x * 256 + threadIdx.x; i < nf4;
         i += (size_t)gridDim.x * 256) {
        const u32 b   = (u32)(i >> 16);          // 65536 float4 per tree
        const u32 rem = (u32)(i & 65535u);
        const u32 r   = rem >> 7;                // 128 float4 per row
        const u32 c0  = (rem & 127u) << 2;
        float4 v;
        v.x = (r == c0 + 0) ? 1.f : 0.f;
        v.y = (r == c0 + 1) ? 1.f : 0.f;
        v.z = (r == c0 + 2) ? 1.f : 0.f;
        v.w = (r == c0 + 3) ? 1.f : 0.f;
        *reinterpret_cast<float4*>(out + (size_t)b * TOTAL * NTIPS
                                   + (size_t)r * NTIPS + c0) = v;
    }
}

// ---------------------------------------------------------------------------
// copyfinal (fallback only, slots in d_out): resolved slot -> ws verbatim.
// ---------------------------------------------------------------------------
__global__ __launch_bounds__(256) void copyfinal_kernel(
        const int* __restrict__ ctrl, const u16* __restrict__ slots,
        u16* __restrict__ dst) {
    int T, slot, fromX0;
    resolveS(ctrl[0], T, slot, fromX0);
    if (fromX0) return;
    const uint4* src = reinterpret_cast<const uint4*>(slots + (size_t)slot * XB);
    uint4* d = reinterpret_cast<uint4*>(dst);
    const size_t n = XB / 8;
    for (size_t i = (size_t)blockIdx.x * 256 + threadIdx.x; i < n;
         i += (size_t)gridDim.x * 256)
        d[i] = src[i];
}

// ---------------------------------------------------------------------------
// phaseCX: resume from resolved checkpoint, run T (==0 common case) steps,
// write the X block (rows 512..1021) as fp32. Self-resolves S when
// ctrl[2]==0. T==0 fast path: skip offset build + const-row init entirely.
// ---------------------------------------------------------------------------
__global__ __launch_bounds__(256, 4) void phaseCX_kernel(
        const int* __restrict__ edge, const float* __restrict__ partials,
        const int* __restrict__ ctrl, const u16* __restrict__ s0, int ring,
        float* __restrict__ out) {
    __shared__ u16 X[BSTR2];
    __shared__ int sS;

    const int wg = blockIdx.x, b = wg >> 5, sl = wg & 31;   // 16-feat slab
    const int tid = threadIdx.x;

    // ---- resolve S (common: ctrl; rare: in-kernel findS scan) ----
    const int found = ctrl[2];
    if (found != 0) {
        if (tid == 0) sS = ctrl[0];
    } else if (tid < 64) {                   // wave 0 = EXACT findS math
        const int sStart = (ctrl[3] > 1) ? ctrl[3] : 1;
        const float tol_bf = bf2f(f2bf(1e-5f));
        int S = -1;
        for (int s = sStart; s <= ITERS; ++s) {
            const float* p = partials + ((size_t)(s - 1) * BS + tid) * NSLAB;
            float t = 0.f;
            #pragma unroll
            for (int k = 0; k < NSLAB; ++k) t += p[k];
            const float lnorm = bf2f(f2bf(t / 261120.0f));
            if (__ballot(lnorm > tol_bf) == 0ULL) { S = s; break; }
        }
        if (S < 0) S = ITERS;                // cap at MAX_ITERS
        if (tid == 0) sS = S;
    }
    __syncthreads();
    int T, slot, fromX0;
    resolveS(sS, T, slot, fromX0);

    const int rg = tid >> 2;                 // row group 0..63
    const int l  = tid & 3;
    const int lbyte = l << 3;
    const int nr = (rg < 62) ? 8 : 7;
    char* Xc = reinterpret_cast<char*>(X);
    const u32 r0b = (u32)(rg * 32 + lbyte);

    u32 offB[8][3];
    if (T > 0) {                             // offsets only needed for steps
        #pragma unroll
        for (int k = 0; k < 8; ++k) if (k < nr) {
            const int i = rg + (k << 6);
            const int* ep = edge + ((size_t)b * TOTAL + NTIPS + i) * 3;
            #pragma unroll
            for (int t = 0; t < 3; ++t) {
                const int e = ep[t];
                u32 off;
                if (e >= NTIPS)          off = (u32)((e - NTIPS) * ROWEL2);
                else if ((e >> 4) == sl) off = (u32)(ONE2 + (e & 15) * ROWEL2);
                else                     off = (u32)ZROW2;
                offB[k][t] = off * 2u + (u32)lbyte;
            }
        }
    }

    if (fromX0) {
        for (int j = tid; j < XSEC2 / 2; j += 256)
            reinterpret_cast<u32*>(X)[j] = 0x3B003B00u;
    } else {
        // translate from 8-feat slab-major snapshot (R7..R11-proven)
        const char* src = reinterpret_cast<const char*>(s0)
                        + (ring ? (size_t)slot * SLOTB : (size_t)0);
        const u32 sb = (u32)(b * NSLAB + sl * 2 + (l >> 1)) * (u32)WGB
                     + (u32)((l & 1) << 3);
        #pragma unroll
        for (int k = 0; k < 8; ++k) if (k < nr) {
            const int r = rg + (k << 6);
            *reinterpret_cast<uint2*>(Xc + r0b + (k << 11)) =
                *reinterpret_cast<const uint2*>(src + sb + (u32)(r * 16));
        }
    }
    if (T > 0) {                             // const rows only feed steps
        for (int j = tid; j < 17 * ROWEL2; j += 256) {
            const int row = j >> 4, col = j & 15;
            X[ONE2 + j] = (row == col) ? (u16)0x3F80 : (u16)0;
        }
    }
    __syncthreads();                         // cross-thread rows for write

    for (int t = 1; t <= T; ++t) {
        uint2 nv[8];
        #pragma unroll
        for (int k = 0; k < 8; ++k) if (k < nr) {
            const uint2 g0 = *reinterpret_cast<const uint2*>(Xc + offB[k][0]);
            const uint2 g1 = *reinterpret_cast<const uint2*>(Xc + offB[k][1]);
            const uint2 g2 = *reinterpret_cast<const uint2*>(Xc + offB[k][2]);
            nv[k].x = stepND(g0.x, g1.x, g2.x);
            nv[k].y = stepND(g0.y, g1.y, g2.y);
        }
        __syncthreads();
        #pragma unroll
        for (int k = 0; k < 8; ++k) if (k < nr)
            *reinterpret_cast<uint2*>(Xc + r0b + (k << 11)) = nv[k];
        __syncthreads();
    }

    // X block: WG owns feature cols [sl*16, sl*16+16) of tree b.
    float* xbase = out + (size_t)b * TOTAL * NTIPS
                 + (size_t)NTIPS * NTIPS + sl * 16;
    for (int j = tid; j < DIM * 4; j += 256) {
        const int r = j >> 2, c4 = (j & 3) << 2;
        const ushort4 a = *reinterpret_cast<const ushort4*>(&X[r * ROWEL2 + c4]);
        float4 v;
        v.x = bf2f(a.x); v.y = bf2f(a.y); v.z = bf2f(a.z); v.w = bf2f(a.w);
        *reinterpret_cast<float4*>(xbase + (size_t)r * NTIPS + c4) = v;
    }
}

extern "C" void kernel_launch(void* const* d_in, const int* in_sizes, int n_in,
                              void* d_out, int out_size, void* d_ws, size_t ws_size,
                              hipStream_t stream) {
    const int* edge = (const int*)d_in[1];       // (BS, TOTAL, 3) int32
    float* out = (float*)d_out;
    const size_t partB = NPART * sizeof(float);

    if (ws_size >= 2 * SLOTB + partB + 256) {
        // ---- primary: 2-slot ring in ws; 4 dispatches ----
        u16*   slots    = (u16*)d_ws;
        float* partials = (float*)((char*)d_ws + 2 * SLOTB);
        int*   ctrl     = (int*)((char*)partials + partB);
        live12_kernel<<<NWG, 256, 0, stream>>>(edge, partials, ctrl, slots,
                                               out, 1);
        findS_kernel<<<1, 64, 0, stream>>>(partials, ctrl, 12);
        tail_kernel<<<NWG, 256, 0, stream>>>(edge, partials, ctrl, slots);
        phaseCX_kernel<<<NWG2, 256, 0, stream>>>(edge, partials, ctrl,
                                                 slots, 1, out);
    } else {
        // ---- fallback: 2-slot ring in d_out; extract, then ident, then X ----
        u16*   slots    = (u16*)d_out;
        u16*   finalX   = (u16*)d_ws;
        float* partials = (float*)((char*)d_ws + SLOTB);
        int*   ctrl     = (int*)((char*)partials + partB);
        live12_kernel<<<NWG, 256, 0, stream>>>(edge, partials, ctrl, slots,
                                               nullptr, 0);
        findS_kernel<<<1, 64, 0, stream>>>(partials, ctrl, 12);
        tail_kernel<<<NWG, 256, 0, stream>>>(edge, partials, ctrl, slots);
        findS_kernel<<<1, 64, 0, stream>>>(partials, ctrl, 50);
        copyfinal_kernel<<<2048, 256, 0, stream>>>(ctrl, slots, finalX);
        ident_kernel<<<2048, 256, 0, stream>>>(out);
        phaseCX_kernel<<<NWG2, 256, 0, stream>>>(edge, partials, ctrl,
                                                 finalX, 0, out);
    }
}

// Round 14
// 242.340 us; speedup vs baseline: 1.0962x; 1.0962x over previous
//
#include <hip/hip_runtime.h>

// ---- problem geometry ----
#define NTIPS 512
#define DIM   510                     // internal nodes = ntips - 2
#define TOTAL 1022
#define BS    64
#define ITERS 50

// ---- chunk config: 8-feat slabs (R4/R7/R9/R10-proven uint2 body), dbuf ----
#define NSLAB 64
#define NWG   (BS * NSLAB)            // 4096 workgroups
#define NPART ((size_t)ITERS * BS * NSLAB)
#define ROWEL 8                       // u16 per row-slab (16 B)
#define XSEC   (DIM * ROWEL)          // 4080 u16
#define ONEOFF XSEC                   // 8 one-hot const rows
#define ZROW   (XSEC + 8 * ROWEL)     // all-zero const row
#define BSTRIDE (XSEC + 9 * ROWEL)    // 4152 u16 per LDS buffer
#define BUFB   (BSTRIDE * 2)          // 8304 B per buffer (2 buffers = 16.6KB)
#define WGB    (DIM * ROWEL * 2)      // 8160 B per WG region in a slot
#define XB     ((size_t)BS * DIM * NTIPS)  // u16 per snapshot slot
#define SLOTB  (XB * 2)               // 33.4 MB per slot

// ---- phaseC config: 16-feat slabs, single-buffer ----
#define NSLAB2 32
#define NWG2   (BS * NSLAB2)          // 2048 workgroups
#define ROWEL2 16
#define XSEC2  (DIM * ROWEL2)         // 8160 u16
#define ONE2   XSEC2
#define ZROW2  (XSEC2 + 16 * ROWEL2)
#define BSTR2  (XSEC2 + 17 * ROWEL2)  // 8432 u16 = 16864 B

typedef unsigned short u16;
typedef unsigned int   u32;
typedef float f32x2 __attribute__((ext_vector_type(2)));

// bf16 RNE helpers (validated chain)
__device__ __forceinline__ u16 f2bf(float x) {
    u32 u = __float_as_uint(x);
    return (u16)((u + 0x7FFFu + ((u >> 16) & 1u)) >> 16);
}
__device__ __forceinline__ float bf2f(u16 h) { return __uint_as_float(((u32)h) << 16); }
__device__ __forceinline__ float bflo(u32 p) { return __uint_as_float(p << 16); }
__device__ __forceinline__ float bfhi(u32 p) { return __uint_as_float(p & 0xFFFF0000u); }
__device__ __forceinline__ f32x2 unpk(u32 p) {
    f32x2 r; r.x = bflo(p); r.y = bfhi(p); return r;
}

#if defined(__has_builtin)
#  if __has_builtin(__builtin_amdgcn_cvt_pk_bf16_f32)
#    define HAVE_PKBF 1
#  endif
#endif
#ifdef HAVE_PKBF
typedef __bf16 bf16x2 __attribute__((ext_vector_type(2)));
__device__ __forceinline__ u32 pkbf(float a, float b) {   // lo=a, hi=b, RNE
    bf16x2 r = __builtin_amdgcn_cvt_pk_bf16_f32(a, b);
    return __builtin_bit_cast(u32, r);
}
#else
__device__ __forceinline__ u32 pkbf(float a, float b) {
    return (u32)f2bf(a) | ((u32)f2bf(b) << 16);
}
#endif

// correctly-rounded f32 /3 (Markstein mul+2fma) — R2..R12-validated
__device__ __forceinline__ f32x2 div3v(f32x2 x) {
    const float C = 0x1.555556p-2f;               // RN(1/3)
    f32x2 q0, r, q;
    q0.x = x.x * C;             q0.y = x.y * C;
    r.x = fmaf(-3.f, q0.x, x.x); r.y = fmaf(-3.f, q0.y, x.y);
    q.x = fmaf(r.x, C, q0.x);    q.y = fmaf(r.y, C, q0.y);
    return q;
}
// no-delta packed-pair step (phaseC)
__device__ __forceinline__ u32 stepND(u32 a0, u32 a1, u32 a2) {
    const f32x2 a = (unpk(a0) + unpk(a1)) + unpk(a2);
    const f32x2 q = div3v(a);
    return pkbf(q.x, q.y);
}

// LDS-only barrier (R3..R12-validated): no vmcnt drain
__device__ __forceinline__ void barrier_lds_only() {
    __builtin_amdgcn_sched_barrier(0);
    asm volatile("s_waitcnt lgkmcnt(0)" ::: "memory");
    __builtin_amdgcn_s_barrier();
    __builtin_amdgcn_sched_barrier(0);
}

// Surviving-checkpoint map (R13):
//  live12 leaves ONLY cp9 (slot 0) — no end checkpoint (end-drain cost, R12).
//  tail (runs iff S>12) leaves cp44 (slot 1) + cp50 (slot 0); cp9 destroyed.
//  S in (12,43]: resume X0 (slow-but-correct; never taken for this data).
__device__ __forceinline__ void resolveS(int S, int& T, int& slot, int& fromX0) {
    fromX0 = 0;
    if (S >= 50)      { T = 0;      slot = 0; }
    else if (S >= 44) { T = S - 44; slot = 1; }
    else if (S >= 13) { T = S;      slot = 0; fromX0 = 1; }
    else if (S >= 9)  { T = S - 9;  slot = 0; }
    else              { T = S;      slot = 0; fromX0 = 1; }
}

// gather offsets for 8-feat slabs (BYTE units, buffer-relative) — R4-proven
__device__ __forceinline__ void make_offsets8(const int* __restrict__ edge,
        int b, int sl, int rg, int lbyte, int nr, u32 offB[4][3]) {
    #pragma unroll
    for (int k = 0; k < 4; ++k) if (k < nr) {
        const int i = rg + 128 * k;
        const int* ep = edge + ((size_t)b * TOTAL + NTIPS + i) * 3;
        #pragma unroll
        for (int t = 0; t < 3; ++t) {
            const int e = ep[t];
            u32 off;
            if (e >= NTIPS)          off = (u32)((e - NTIPS) * ROWEL);
            else if ((e >> 3) == sl) off = (u32)(ONEOFF + (e & 7) * ROWEL);
            else                     off = (u32)ZROW;
            offB[k][t] = off * 2u + (u32)lbyte;
        }
    }
}

__device__ __forceinline__ void init_const_rows8(u16* X, int tid) {
    for (int j = tid; j < 9 * ROWEL; j += 256) {
        const int row = j >> 3, col = j & 7;
        const u16 v = (row == col) ? (u16)0x3F80 : (u16)0;  // row 8 = zeros
        X[ONEOFF + j] = v;
        X[BSTRIDE + ONEOFF + j] = v;
    }
}

// ---------------------------------------------------------------------------
// live12: steps 1..12 in ONE launch. Fused identity write + ctrl clear
// (R11-proven). SINGLE checkpoint: cp9 (u==8 -> slot 0), fully drained
// under steps 10-12. NO end checkpoint — R12 showed end-of-kernel s_endpgm
// waits ~volume/1.4TB/s for in-flight stores; keeping end-state out of
// global removes that stall. phaseCX/tail resume from cp9 instead.
// ---------------------------------------------------------------------------
__global__ __launch_bounds__(256, 8) void live12_kernel(
        const int* __restrict__ edge, float* __restrict__ partials,
        int* __restrict__ ctrl, u16* __restrict__ slots,
        float* __restrict__ out, int doIdent) {
    __shared__ u16 X[2 * BSTRIDE];
    __shared__ float redL[2][4];

    const int wg = blockIdx.x, b = wg >> 6, sl = wg & 63;
    const int tid = threadIdx.x, rg = tid >> 1;
    const int lbyte = (tid & 1) << 3;
    const int nr = (rg < 126) ? 4 : 3;
    char* Xc = reinterpret_cast<char*>(X);
    const u32 r0b = (u32)(rg * 16 + lbyte);

    if (wg == 0 && tid == 0) {               // ctrl clear (was host memset)
        ctrl[0] = 0; ctrl[1] = 0; ctrl[2] = 0; ctrl[3] = 0;
    }
    if (doIdent) {                           // identity stripe: rows sl*8..+7
        const int r = (sl << 3) + (tid >> 5);
        const int c0 = (tid & 31) << 4;      // 16 floats per thread
        float* drow = out + ((size_t)b * TOTAL + r) * NTIPS + c0;
        #pragma unroll
        for (int m = 0; m < 4; ++m) {
            const int cb = c0 + (m << 2);
            float4 v;
            v.x = (r == cb + 0) ? 1.f : 0.f;
            v.y = (r == cb + 1) ? 1.f : 0.f;
            v.z = (r == cb + 2) ? 1.f : 0.f;
            v.w = (r == cb + 3) ? 1.f : 0.f;
            *reinterpret_cast<float4*>(drow + (m << 2)) = v;
        }
    }

    u32 offB[4][3];
    make_offsets8(edge, b, sl, rg, lbyte, nr, offB);

    u32 rowByte[4];
    #pragma unroll
    for (int k = 0; k < 4; ++k)
        rowByte[k] = (u32)wg * (u32)WGB + (u32)((rg + 128 * k) * 16) + (u32)lbyte;

    for (int j = tid; j < XSEC / 2; j += 256)
        reinterpret_cast<u32*>(X)[j] = 0x3B003B00u;       // X0 = bf16(1/512)
    init_const_rows8(X, tid);

    f32x2 old01[4], old23[4];
    #pragma unroll
    for (int k = 0; k < 4; ++k) if (k < nr) {
        const uint2 ov = *reinterpret_cast<const uint2*>(Xc + r0b + (k << 11));
        old01[k] = unpk(ov.x); old23[k] = unpk(ov.y);
    }
    __syncthreads();

    char* cp9C = reinterpret_cast<char*>(slots);          // cp9 -> slot 0
    #pragma unroll
    for (int u = 0; u < 12; ++u) {
        const int s = 1 + u;
        const int srcB = (u & 1) ? BUFB : 0;
        const int dstB = ((u + 1) & 1) ? BUFB : 0;
        float dacc = 0.f;
        #pragma unroll
        for (int k = 0; k < 4; ++k) if (k < nr) {
            const uint2 g0 = *reinterpret_cast<const uint2*>(Xc + offB[k][0] + srcB);
            const uint2 g1 = *reinterpret_cast<const uint2*>(Xc + offB[k][1] + srcB);
            const uint2 g2 = *reinterpret_cast<const uint2*>(Xc + offB[k][2] + srcB);
            const f32x2 a01 = (unpk(g0.x) + unpk(g1.x)) + unpk(g2.x);
            const f32x2 a23 = (unpk(g0.y) + unpk(g1.y)) + unpk(g2.y);
            const f32x2 q01 = div3v(a01), q23 = div3v(a23);
            uint2 nv;
            nv.x = pkbf(q01.x, q01.y);
            nv.y = pkbf(q23.x, q23.y);
            *reinterpret_cast<uint2*>(Xc + r0b + ((k << 11) + dstB)) = nv;
            if (u == 8)                              // step 9 checkpoint
                *reinterpret_cast<uint2*>(cp9C + rowByte[k]) = nv;
            const f32x2 n01 = unpk(nv.x), n23 = unpk(nv.y);
            const f32x2 d01v = n01 - old01[k];
            const f32x2 d23v = n23 - old23[k];
            const u32 d01 = pkbf(d01v.x, d01v.y);
            const u32 d23 = pkbf(d23v.x, d23v.y);
            dacc += fabsf(bflo(d01));
            dacc += fabsf(bfhi(d01));
            dacc += fabsf(bflo(d23));
            dacc += fabsf(bfhi(d23));
            old01[k] = n01; old23[k] = n23;
        }
        #pragma unroll
        for (int off = 32; off > 0; off >>= 1) dacc += __shfl_down(dacc, off);
        if ((tid & 63) == 0) redL[u & 1][tid >> 6] = dacc;
        barrier_lds_only();
        if (tid == 0) {
            const float dtot = ((redL[u & 1][0] + redL[u & 1][1])
                                + redL[u & 1][2]) + redL[u & 1][3];
            partials[((size_t)(s - 1) * BS + b) * NSLAB + sl] = dtot;
        }
    }
    // no end checkpoint — nothing large in flight at s_endpgm
}

// ---------------------------------------------------------------------------
// tail: steps 10..50 in ONE gated launch (resumes from cp9, slot 0; the
// 3 re-run steps 10-12 write bit-identical partials). Checkpoints at
// 44 (slot 1) and 50 (slot 0) for phaseCX's S>12 paths.
// ---------------------------------------------------------------------------
__global__ __launch_bounds__(256, 8) void tail_kernel(
        const int* __restrict__ edge, float* __restrict__ partials,
        const int* __restrict__ ctrl, u16* __restrict__ slots) {
    if (ctrl[2] != 0) return;                    // common case: skip

    __shared__ u16 X[2 * BSTRIDE];
    __shared__ float redL[2][4];

    const int wg = blockIdx.x, b = wg >> 6, sl = wg & 63;
    const int tid = threadIdx.x, rg = tid >> 1;
    const int lbyte = (tid & 1) << 3;
    const int nr = (rg < 126) ? 4 : 3;
    char* Xc = reinterpret_cast<char*>(X);
    const u32 r0b = (u32)(rg * 16 + lbyte);

    u32 offB[4][3];
    make_offsets8(edge, b, sl, rg, lbyte, nr, offB);

    u32 rowByte[4];
    #pragma unroll
    for (int k = 0; k < 4; ++k)
        rowByte[k] = (u32)wg * (u32)WGB + (u32)((rg + 128 * k) * 16) + (u32)lbyte;

    {   // reload checkpoint step 9 (slot 0)
        const char* src0 = reinterpret_cast<const char*>(slots);
        #pragma unroll
        for (int k = 0; k < 4; ++k) if (k < nr)
            *reinterpret_cast<uint2*>(Xc + r0b + (k << 11)) =
                *reinterpret_cast<const uint2*>(src0 + rowByte[k]);
    }
    init_const_rows8(X, tid);

    f32x2 old01[4], old23[4];
    #pragma unroll
    for (int k = 0; k < 4; ++k) if (k < nr) {
        const uint2 ov = *reinterpret_cast<const uint2*>(Xc + r0b + (k << 11));
        old01[k] = unpk(ov.x); old23[k] = unpk(ov.y);
    }
    __syncthreads();

    u32 srcB = 0;
    for (int s = 10; s <= 50; ++s) {
        const u32 dstB = srcB ^ (u32)BUFB;
        float dacc = 0.f;
        #pragma unroll
        for (int k = 0; k < 4; ++k) if (k < nr) {
            const uint2 g0 = *reinterpret_cast<const uint2*>(Xc + offB[k][0] + srcB);
            const uint2 g1 = *reinterpret_cast<const uint2*>(Xc + offB[k][1] + srcB);
            const uint2 g2 = *reinterpret_cast<const uint2*>(Xc + offB[k][2] + srcB);
            const f32x2 a01 = (unpk(g0.x) + unpk(g1.x)) + unpk(g2.x);
            const f32x2 a23 = (unpk(g0.y) + unpk(g1.y)) + unpk(g2.y);
            const f32x2 q01 = div3v(a01), q23 = div3v(a23);
            uint2 nv;
            nv.x = pkbf(q01.x, q01.y);
            nv.y = pkbf(q23.x, q23.y);
            *reinterpret_cast<uint2*>(Xc + r0b + ((k << 11) + dstB)) = nv;
            const f32x2 n01 = unpk(nv.x), n23 = unpk(nv.y);
            const f32x2 d01v = n01 - old01[k];
            const f32x2 d23v = n23 - old23[k];
            const u32 d01 = pkbf(d01v.x, d01v.y);
            const u32 d23 = pkbf(d23v.x, d23v.y);
            dacc += fabsf(bflo(d01));
            dacc += fabsf(bfhi(d01));
            dacc += fabsf(bflo(d23));
            dacc += fabsf(bfhi(d23));
            old01[k] = n01; old23[k] = n23;
        }
        #pragma unroll
        for (int off = 32; off > 0; off >>= 1) dacc += __shfl_down(dacc, off);
        if ((tid & 63) == 0) redL[s & 1][tid >> 6] = dacc;
        barrier_lds_only();
        if (tid == 0) {
            const float dtot = ((redL[s & 1][0] + redL[s & 1][1])
                                + redL[s & 1][2]) + redL[s & 1][3];
            partials[((size_t)(s - 1) * BS + b) * NSLAB + sl] = dtot;
        }
        if (s == 44 || s == 50) {                // surviving cps (S>12 only)
            char* slotC = reinterpret_cast<char*>(slots)
                        + (size_t)(s == 44 ? 1 : 0) * SLOTB;
            #pragma unroll
            for (int k = 0; k < 4; ++k) if (k < nr)
                *reinterpret_cast<uint2*>(slotC + rowByte[k]) =
                    *reinterpret_cast<const uint2*>(Xc + r0b + ((k << 11) + dstB));
        }
        srcB = dstB;
    }
}

// ---------------------------------------------------------------------------
// findS: incremental (ctrl[3] = next unscanned s). EXACT decision math.
// ---------------------------------------------------------------------------
__global__ void findS_kernel(const float* __restrict__ partials,
                             int* __restrict__ ctrl, int smax) {
    if (ctrl[2] != 0) return;
    const int lane = threadIdx.x;
    const int sStart = (ctrl[3] > 1) ? ctrl[3] : 1;
    const float tol_bf = bf2f(f2bf(1e-5f));
    int S = -1;
    for (int s = sStart; s <= smax; ++s) {
        const float* p = partials + ((size_t)(s - 1) * BS + lane) * NSLAB;
        float t = 0.f;
        #pragma unroll
        for (int k = 0; k < NSLAB; ++k) t += p[k];
        const float lnorm = bf2f(f2bf(t / 261120.0f));
        if (__ballot(lnorm > tol_bf) == 0ULL) { S = s; break; }
    }
    if (S < 0 && smax == ITERS) S = ITERS;
    if (lane == 0) {
        if (S > 0) { ctrl[0] = S; ctrl[2] = 1; }
        else         ctrl[3] = smax + 1;
    }
}

// ---------------------------------------------------------------------------
// ident (fallback only): identity block, row-contiguous full-BW writer.
// ---------------------------------------------------------------------------
__global__ __launch_bounds__(256) void ident_kernel(float* __restrict__ out) {
    const size_t nf4 = (size_t)BS * NTIPS * NTIPS / 4;   // 4,194,304 float4
    for (size_t i = (size_t)blockIdx.x * 256 + threadIdx.x; i < nf4;
         i += (size_t)gridDim.x * 256) {
        const u32 b   = (u32)(i >> 16);          // 65536 float4 per tree
        const u32 rem = (u32)(i & 65535u);
        const u32 r   = rem >> 7;                // 128 float4 per row
        const u32 c0  = (rem & 127u) << 2;
        float4 v;
        v.x = (r == c0 + 0) ? 1.f : 0.f;
        v.y = (r == c0 + 1) ? 1.f : 0.f;
        v.z = (r == c0 + 2) ? 1.f : 0.f;
        v.w = (r == c0 + 3) ? 1.f : 0.f;
        *reinterpret_cast<float4*>(out + (size_t)b * TOTAL * NTIPS
                                   + (size_t)r * NTIPS + c0) = v;
    }
}

// ---------------------------------------------------------------------------
// copyfinal (fallback only, slots in d_out): resolved slot -> ws verbatim.
// ---------------------------------------------------------------------------
__global__ __launch_bounds__(256) void copyfinal_kernel(
        const int* __restrict__ ctrl, const u16* __restrict__ slots,
        u16* __restrict__ dst) {
    int T, slot, fromX0;
    resolveS(ctrl[0], T, slot, fromX0);
    if (fromX0) return;
    const uint4* src = reinterpret_cast<const uint4*>(slots + (size_t)slot * XB);
    uint4* d = reinterpret_cast<uint4*>(dst);
    const size_t n = XB / 8;
    for (size_t i = (size_t)blockIdx.x * 256 + threadIdx.x; i < n;
         i += (size_t)gridDim.x * 256)
        d[i] = src[i];
}

// ---------------------------------------------------------------------------
// phaseCX: resume from resolved checkpoint, run T (=2 common case, S=11)
// steps, write the X block (rows 512..1021) as fp32. Self-resolves S when
// ctrl[2]==0. T==0 fast path skips offset build + const-row init.
// ---------------------------------------------------------------------------
__global__ __launch_bounds__(256, 4) void phaseCX_kernel(
        const int* __restrict__ edge, const float* __restrict__ partials,
        const int* __restrict__ ctrl, const u16* __restrict__ s0, int ring,
        float* __restrict__ out) {
    __shared__ u16 X[BSTR2];
    __shared__ int sS;

    const int wg = blockIdx.x, b = wg >> 5, sl = wg & 31;   // 16-feat slab
    const int tid = threadIdx.x;

    // ---- resolve S (common: ctrl; rare: in-kernel findS scan) ----
    const int found = ctrl[2];
    if (found != 0) {
        if (tid == 0) sS = ctrl[0];
    } else if (tid < 64) {                   // wave 0 = EXACT findS math
        const int sStart = (ctrl[3] > 1) ? ctrl[3] : 1;
        const float tol_bf = bf2f(f2bf(1e-5f));
        int S = -1;
        for (int s = sStart; s <= ITERS; ++s) {
            const float* p = partials + ((size_t)(s - 1) * BS + tid) * NSLAB;
            float t = 0.f;
            #pragma unroll
            for (int k = 0; k < NSLAB; ++k) t += p[k];
            const float lnorm = bf2f(f2bf(t / 261120.0f));
            if (__ballot(lnorm > tol_bf) == 0ULL) { S = s; break; }
        }
        if (S < 0) S = ITERS;                // cap at MAX_ITERS
        if (tid == 0) sS = S;
    }
    __syncthreads();
    int T, slot, fromX0;
    resolveS(sS, T, slot, fromX0);

    const int rg = tid >> 2;                 // row group 0..63
    const int l  = tid & 3;
    const int lbyte = l << 3;
    const int nr = (rg < 62) ? 8 : 7;
    char* Xc = reinterpret_cast<char*>(X);
    const u32 r0b = (u32)(rg * 32 + lbyte);

    u32 offB[8][3];
    if (T > 0) {                             // offsets only needed for steps
        #pragma unroll
        for (int k = 0; k < 8; ++k) if (k < nr) {
            const int i = rg + (k << 6);
            const int* ep = edge + ((size_t)b * TOTAL + NTIPS + i) * 3;
            #pragma unroll
            for (int t = 0; t < 3; ++t) {
                const int e = ep[t];
                u32 off;
                if (e >= NTIPS)          off = (u32)((e - NTIPS) * ROWEL2);
                else if ((e >> 4) == sl) off = (u32)(ONE2 + (e & 15) * ROWEL2);
                else                     off = (u32)ZROW2;
                offB[k][t] = off * 2u + (u32)lbyte;
            }
        }
    }

    if (fromX0) {
        for (int j = tid; j < XSEC2 / 2; j += 256)
            reinterpret_cast<u32*>(X)[j] = 0x3B003B00u;
    } else {
        // translate from 8-feat slab-major snapshot (R7..R12-proven)
        const char* src = reinterpret_cast<const char*>(s0)
                        + (ring ? (size_t)slot * SLOTB : (size_t)0);
        const u32 sb = (u32)(b * NSLAB + sl * 2 + (l >> 1)) * (u32)WGB
                     + (u32)((l & 1) << 3);
        #pragma unroll
        for (int k = 0; k < 8; ++k) if (k < nr) {
            const int r = rg + (k << 6);
            *reinterpret_cast<uint2*>(Xc + r0b + (k << 11)) =
                *reinterpret_cast<const uint2*>(src + sb + (u32)(r * 16));
        }
    }
    if (T > 0) {                             // const rows only feed steps
        for (int j = tid; j < 17 * ROWEL2; j += 256) {
            const int row = j >> 4, col = j & 15;
            X[ONE2 + j] = (row == col) ? (u16)0x3F80 : (u16)0;
        }
    }
    __syncthreads();                         // cross-thread rows for write

    for (int t = 1; t <= T; ++t) {
        uint2 nv[8];
        #pragma unroll
        for (int k = 0; k < 8; ++k) if (k < nr) {
            const uint2 g0 = *reinterpret_cast<const uint2*>(Xc + offB[k][0]);
            const uint2 g1 = *reinterpret_cast<const uint2*>(Xc + offB[k][1]);
            const uint2 g2 = *reinterpret_cast<const uint2*>(Xc + offB[k][2]);
            nv[k].x = stepND(g0.x, g1.x, g2.x);
            nv[k].y = stepND(g0.y, g1.y, g2.y);
        }
        __syncthreads();
        #pragma unroll
        for (int k = 0; k < 8; ++k) if (k < nr)
            *reinterpret_cast<uint2*>(Xc + r0b + (k << 11)) = nv[k];
        __syncthreads();
    }

    // X block: WG owns feature cols [sl*16, sl*16+16) of tree b.
    float* xbase = out + (size_t)b * TOTAL * NTIPS
                 + (size_t)NTIPS * NTIPS + sl * 16;
    for (int j = tid; j < DIM * 4; j += 256) {
        const int r = j >> 2, c4 = (j & 3) << 2;
        const ushort4 a = *reinterpret_cast<const ushort4*>(&X[r * ROWEL2 + c4]);
        float4 v;
        v.x = bf2f(a.x); v.y = bf2f(a.y); v.z = bf2f(a.z); v.w = bf2f(a.w);
        *reinterpret_cast<float4*>(xbase + (size_t)r * NTIPS + c4) = v;
    }
}

extern "C" void kernel_launch(void* const* d_in, const int* in_sizes, int n_in,
                              void* d_out, int out_size, void* d_ws, size_t ws_size,
                              hipStream_t stream) {
    const int* edge = (const int*)d_in[1];       // (BS, TOTAL, 3) int32
    float* out = (float*)d_out;
    const size_t partB = NPART * sizeof(float);

    if (ws_size >= 2 * SLOTB + partB + 256) {
        // ---- primary: 2-slot ring in ws; 4 dispatches ----
        u16*   slots    = (u16*)d_ws;
        float* partials = (float*)((char*)d_ws + 2 * SLOTB);
        int*   ctrl     = (int*)((char*)partials + partB);
        live12_kernel<<<NWG, 256, 0, stream>>>(edge, partials, ctrl, slots,
                                               out, 1);
        findS_kernel<<<1, 64, 0, stream>>>(partials, ctrl, 12);
        tail_kernel<<<NWG, 256, 0, stream>>>(edge, partials, ctrl, slots);
        phaseCX_kernel<<<NWG2, 256, 0, stream>>>(edge, partials, ctrl,
                                                 slots, 1, out);
    } else {
        // ---- fallback: 2-slot ring in d_out; extract, then ident, then X ----
        u16*   slots    = (u16*)d_out;
        u16*   finalX   = (u16*)d_ws;
        float* partials = (float*)((char*)d_ws + SLOTB);
        int*   ctrl     = (int*)((char*)partials + partB);
        live12_kernel<<<NWG, 256, 0, stream>>>(edge, partials, ctrl, slots,
                                               nullptr, 0);
        findS_kernel<<<1, 64, 0, stream>>>(partials, ctrl, 12);
        tail_kernel<<<NWG, 256, 0, stream>>>(edge, partials, ctrl, slots);
        findS_kernel<<<1, 64, 0, stream>>>(partials, ctrl, 50);
        copyfinal_kernel<<<2048, 256, 0, stream>>>(ctrl, slots, finalX);
        ident_kernel<<<2048, 256, 0, stream>>>(out);
        phaseCX_kernel<<<NWG2, 256, 0, stream>>>(edge, partials, ctrl,
                                                 finalX, 0, out);
    }
}